// Round 8
// baseline (184.687 us; speedup 1.0000x reference)
//
#include <hip/hip_runtime.h>
#include <cstring>

#define D 128
#define ROW 16512                 // D + D*D
#define DTF (1.0f/4095.0f)
#define HSTEP (64.0f/4095.0f)     // Zs scale: Zs = (64*dt)*B
#define H4F  (256.0f/4095.0f)     // coarse checkpoint step
#define LDA 132
#define LDB 132

#define XCP_OFF 4096              // x0 vector
#define MAT_OFF 12416

// slot map (each slot = 16384 floats = one 128x128 matrix)
#define S_ZT      3               // Zs transposed
#define S_V(m)    (4+(m))         // V_m = W0*Zs^m, m=0..6 (row-major)
#define S_AT(J)   (11+(J))        // W(256J)^T, J=0..15
#define S_BMT(J)  (27+(J))        // W(256J+128)^T, J=0..14

// fused-kernel LDS overlay (bytes)
#define XT_OFF   0                // float[128][129]
#define UV_OFF   66048            // chain stage vector (overlaid by uni later)
#define ACC_OFF  66560            // chain k-accumulator
#define UNI_OFF  66048            // U[c][il] 128*68 floats
#define ZA_OFF   100864
#define ZB_OFF   103424
#define KV_OFF   105984
#define XV_OFF   106496
#define RED_OFF  107008
#define CFS_OFF  107520
#define SM_BYTES 108800

struct __align__(16) F4 { float v[4]; };
typedef float f4v __attribute__((ext_vector_type(4)));

__device__ __forceinline__ float* slotp(float* ws, int k){ return ws + MAT_OFF + (size_t)k*16384; }
__device__ __forceinline__ const float* slotpc(const float* ws, int k){ return ws + MAT_OFF + (size_t)k*16384; }

struct CFX { float cf[64][5]; float cx[64][7]; };  // M^i (deg4), M^(64j) (deg6), /64^m scaled
struct CMB { float c[31][7]; };                    // rows: A_J (J=0..15), BM_J (J=0..14)
struct EK  { double e[4][4]; };                    // [z^m](M-1)^k / 64^m, k=1..4, m=1..4

// ---------------- 256-thread strip-matmul pieces ----------------
__device__ __forceinline__ void ldA(const float* A, int r0, float (*As)[LDA]) {
  const F4* A4 = (const F4*)(A + (size_t)r0*128);
  for (int q = threadIdx.x; q < 512; q += 256) {
    F4 x = A4[q];
    *(F4*)&As[q>>5][(q&31)<<2] = x;
  }
}
__device__ __forceinline__ void mmcT(const float (*As)[LDA], const float (*Bs)[LDB], F4& o0, F4& o1) {
  const int rl = threadIdx.x >> 5, c0 = (threadIdx.x & 31) << 2;
  F4 a0s, a1s;
  #pragma unroll
  for (int e = 0; e < 4; ++e) { a0s.v[e] = 0.f; a1s.v[e] = 0.f; }
  #pragma unroll 8
  for (int k = 0; k < 128; ++k) {
    const F4 bv = *(const F4*)&Bs[k][c0];
    const float a0 = As[rl][k], a1 = As[rl+8][k];
    #pragma unroll
    for (int e = 0; e < 4; ++e) {
      a0s.v[e] = fmaf(a0, bv.v[e], a0s.v[e]);
      a1s.v[e] = fmaf(a1, bv.v[e], a1s.v[e]);
    }
  }
  o0 = a0s; o1 = a1s;
}

// ---------------- launch 1: V-chain + misc + Horner A^T/BM^T ----------------
// blocks 0..47:  (m=1..6, strip): V_m strip = W0_strip * Zs^m
// blocks 48..52: out row0 copy + x0
// blocks 53..56: V0 copy
// blocks 57..60: ZT
// blocks 61..308:(mat=0..30, strip): A/BM strip via Horner, written TRANSPOSED
__global__ __launch_bounds__(256) void k_vchain(const float* y0, const float* Bm,
                                                float* ws, float* out, CMB cmb) {
  __shared__ float As[16][LDA];
  __shared__ float Bs[128][LDB];
  int b = blockIdx.x, t = threadIdx.x;
  const float* W0 = y0 + D;
  const int rl = t >> 5, c0 = (t & 31) << 2;
  if (b < 48) {
    int m = (b >> 3) + 1, strip = b & 7;
    const F4* B4 = (const F4*)Bm;
    for (int q = t; q < 4096; q += 256) {
      F4 x = B4[q]; F4 o;
      #pragma unroll
      for (int e = 0; e < 4; ++e) o.v[e] = HSTEP * x.v[e];
      *(F4*)&Bs[q>>5][(q&31)<<2] = o;
    }
    ldA(W0, strip*16, As);
    __syncthreads();
    F4 o0, o1;
    for (int p = 0; p < m; ++p) {
      mmcT(As, Bs, o0, o1);
      if (p+1 < m) {
        __syncthreads();
        *(F4*)&As[rl][c0] = o0;
        *(F4*)&As[rl+8][c0] = o1;
        __syncthreads();
      }
    }
    float* Vp = slotp(ws, S_V(m));
    *(F4*)&Vp[(size_t)(strip*16+rl)*128 + c0]   = o0;
    *(F4*)&Vp[(size_t)(strip*16+rl+8)*128 + c0] = o1;
  } else if (b < 52) {
    int base = (b-48)*1024;
    for (int i = 0; i < 4; ++i) {
      int q = base + t + i*256;
      ((F4*)out)[q] = ((const F4*)y0)[q];
    }
  } else if (b == 52) {
    if (t < 128) { out[16384+t] = y0[16384+t]; ws[XCP_OFF+t] = y0[t]; }
  } else if (b < 57) {
    int base = (b-53)*1024;
    F4* Vp = (F4*)slotp(ws, S_V(0));
    for (int i = 0; i < 4; ++i) { int q = base + t + i*256; Vp[q] = ((const F4*)W0)[q]; }
  } else if (b < 61) {
    int base = (b-57)*1024;
    float* ZT = slotp(ws, S_ZT);
    for (int i = 0; i < 4; ++i) {
      int q = base + t + i*256;
      F4 x = ((const F4*)Bm)[q];
      int r = q>>5, cc2 = (q&31)<<2;
      #pragma unroll
      for (int e = 0; e < 4; ++e) ZT[(size_t)(cc2+e)*128 + r] = HSTEP * x.v[e];
    }
  } else {
    int idx = b - 61;
    int mat = idx >> 3, strip = idx & 7;
    int slot = (mat < 16) ? S_AT(mat) : S_BMT(mat-16);
    const float* cc = cmb.c[mat];
    const F4* B4 = (const F4*)Bm;
    for (int q = t; q < 4096; q += 256) {
      F4 x = B4[q]; F4 o;
      #pragma unroll
      for (int e = 0; e < 4; ++e) o.v[e] = HSTEP * x.v[e];
      *(F4*)&Bs[q>>5][(q&31)<<2] = o;
    }
    const F4 s0 = *(const F4*)&W0[(size_t)(strip*16+rl)*128 + c0];
    const F4 s1 = *(const F4*)&W0[(size_t)(strip*16+rl+8)*128 + c0];
    F4 t0, t1;
    #pragma unroll
    for (int e = 0; e < 4; ++e) { t0.v[e] = cc[6]*s0.v[e]; t1.v[e] = cc[6]*s1.v[e]; }
    *(F4*)&As[rl][c0] = t0; *(F4*)&As[rl+8][c0] = t1;
    __syncthreads();
    F4 o0, o1;
    for (int k = 5; k >= 0; --k) {
      mmcT(As, Bs, o0, o1);
      #pragma unroll
      for (int e = 0; e < 4; ++e) { o0.v[e] += cc[k]*s0.v[e]; o1.v[e] += cc[k]*s1.v[e]; }
      if (k > 0) {
        __syncthreads();
        *(F4*)&As[rl][c0] = o0; *(F4*)&As[rl+8][c0] = o1;
        __syncthreads();
      }
    }
    // write transposed: AT[c][r] = A[r][c]
    float* Cp = slotp(ws, slot);
    int r0 = strip*16 + rl;
    #pragma unroll
    for (int e = 0; e < 4; ++e) {
      Cp[(size_t)(c0+e)*128 + r0]     = o0.v[e];
      Cp[(size_t)(c0+e)*128 + r0 + 8] = o1.v[e];
    }
  }
}

// ---------------- launch 2: fused x-path (chain+Heun) + W fill ----------------
__global__ __launch_bounds__(256) void k_fused(float* ws, float* out, EK ek, CFX cfx) {
  __shared__ __align__(16) char smb[SM_BYTES];
  int t = threadIdx.x;

  if (blockIdx.x >= 64) {
    // ---- W fill: W_{64j+i} = sum_p conv(cf[i],cx[j])[p] * V_p ----
    float (*coefL)[7] = (float (*)[7])smb;
    int bb = blockIdx.x - 64;
    int j = bb >> 4, strip = bb & 15;
    for (int idx = t; idx < 448; idx += 256) {
      int i = idx / 7, p = idx - i*7;
      float s = 0.f;
      #pragma unroll
      for (int m = 0; m <= 4; ++m) {
        int q = p - m;
        float cxv = (q >= 0) ? cfx.cx[j][q] : 0.f;
        s = fmaf(cfx.cf[i][m], cxv, s);
      }
      coefL[i][p] = s;
    }
    int r = strip*8 + (t >> 5);
    int q = r*32 + (t & 31);
    F4 v[7];
    #pragma unroll
    for (int m = 0; m < 7; ++m) v[m] = ((const F4*)slotpc(ws, S_V(m)))[q];
    __syncthreads();
    for (int i = 0; i < 64; ++i) {
      f4v o = {0.f, 0.f, 0.f, 0.f};
      #pragma unroll
      for (int p = 0; p < 7; ++p) {
        float c = coefL[i][p];
        #pragma unroll
        for (int e = 0; e < 4; ++e) o[e] = fmaf(c, v[p].v[e], o[e]);
      }
      __builtin_nontemporal_store(o, (f4v*)(out + (size_t)(j*64 + i)*ROW + D + q*4));
    }
    return;
  }

  // ---- x path ----
  float (*XT)[129] = (float (*)[129])smb;
  float* uv   = (float*)(smb + UV_OFF);
  float* accv = (float*)(smb + ACC_OFF);
  float* uni  = (float*)(smb + UNI_OFF);
  float (*za)[128] = (float (*)[128])(smb + ZA_OFF);
  float (*zb)[128] = (float (*)[128])(smb + ZB_OFF);
  float* kv  = (float*)(smb + KV_OFF);
  float* xv  = (float*)(smb + XV_OFF);
  float* red = (float*)(smb + RED_OFF);
  float (*cfs)[5] = (float (*)[5])(smb + CFS_OFF);

  int J = blockIdx.x >> 2, w = blockIdx.x & 3;
  int r = t & 127, hh = t >> 7;
  if (t < 128) xv[t] = ws[XCP_OFF + t];
  if (t < 64) { // cfs[il][m] = [Zs^m] M^(w*64+il), closed form via binomials
    double di = (double)(w*64 + t);
    double b1 = di, b2 = b1*(di-1.0)*0.5, b3 = b2*(di-2.0)*(1.0/3.0), b4 = b3*(di-3.0)*0.25;
    cfs[t][0] = 1.f;
    cfs[t][1] = (float)(b1*ek.e[0][0]);
    cfs[t][2] = (float)(b1*ek.e[0][1] + b2*ek.e[1][1]);
    cfs[t][3] = (float)(b1*ek.e[0][2] + b2*ek.e[1][2] + b3*ek.e[2][2]);
    cfs[t][4] = (float)(b1*ek.e[0][3] + b2*ek.e[1][3] + b3*ek.e[2][3] + b4*ek.e[3][3]);
  }
  __syncthreads();

  // serial RK4 vector chain: xv = x_{256J} (transposed matrices -> coalesced matvecs)
  const float h = H4F, h2 = 0.5f*H4F, h6 = H4F/6.0f;
  for (int jj = 0; jj < J; ++jj) {
    const float* ATj  = slotpc(ws, S_AT(jj));
    const float* BMTj = slotpc(ws, S_BMT(jj));
    const float* ATn  = slotpc(ws, S_AT(jj+1));
    float s;
    // k1 = A xv
    s = 0.f;
    #pragma unroll 8
    for (int c = hh*64; c < hh*64+64; ++c) s = fmaf(ATj[(size_t)c*128 + r], xv[c], s);
    if (hh) red[r] = s;
    __syncthreads();
    if (!hh) { float k = s + red[r]; accv[r] = k; uv[r] = fmaf(h2, k, xv[r]); }
    __syncthreads();
    // k2 = BM uv
    s = 0.f;
    #pragma unroll 8
    for (int c = hh*64; c < hh*64+64; ++c) s = fmaf(BMTj[(size_t)c*128 + r], uv[c], s);
    if (hh) red[r] = s;
    __syncthreads();
    if (!hh) { float k = s + red[r]; accv[r] += 2.f*k; uv[r] = fmaf(h2, k, xv[r]); }
    __syncthreads();
    // k3 = BM uv
    s = 0.f;
    #pragma unroll 8
    for (int c = hh*64; c < hh*64+64; ++c) s = fmaf(BMTj[(size_t)c*128 + r], uv[c], s);
    if (hh) red[r] = s;
    __syncthreads();
    if (!hh) { float k = s + red[r]; accv[r] += 2.f*k; uv[r] = fmaf(h, k, xv[r]); }
    __syncthreads();
    // k4 = A' uv ; xv += h/6 (acc + k4)
    s = 0.f;
    #pragma unroll 8
    for (int c = hh*64; c < hh*64+64; ++c) s = fmaf(ATn[(size_t)c*128 + r], uv[c], s);
    if (hh) red[r] = s;
    __syncthreads();
    if (!hh) { float k4 = s + red[r]; xv[r] = fmaf(h6, accv[r] + k4, xv[r]); }
    __syncthreads();
  }
  if (J > 0 && w == 0 && t < 128) out[(size_t)(256*J)*ROW + t] = xv[t];

  // stage XT[c][r] = A_J^T (already transposed in ws -> linear copy)
  {
    const F4* ATg = (const F4*)slotpc(ws, S_AT(J));
    for (int q = t; q < 4096; q += 256) {
      F4 x = ATg[q]; int c = q >> 5, r0 = (q & 31) << 2;
      #pragma unroll
      for (int e = 0; e < 4; ++e) XT[c][r0+e] = x.v[e];
    }
  }
  __syncthreads();
  { // k1 = A_J * xv
    float s = 0.f;
    for (int c = hh*64; c < hh*64 + 64; ++c) s = fmaf(XT[c][r], xv[c], s);
    if (hh) red[r] = s;
    __syncthreads();
    if (!hh) kv[r] = s + red[r];
    __syncthreads();
  }
  if (t < 128) { za[0][t] = xv[t]; zb[0][t] = kv[t]; }
  __syncthreads();
  const float* ZTg = slotpc(ws, S_ZT);
  for (int m = 1; m <= 4; ++m) {
    float sa = 0.f, sb = 0.f;
    for (int c = hh*64; c < hh*64 + 64; ++c) {
      float zv = ZTg[(size_t)c*128 + r];
      sa = fmaf(zv, za[m-1][c], sa);
      sb = fmaf(zv, zb[m-1][c], sb);
    }
    if (hh) red[r] = sa;
    __syncthreads();
    if (!hh) za[m][r] = sa + red[r];
    __syncthreads();
    if (hh) red[r] = sb;
    __syncthreads();
    if (!hh) zb[m][r] = sb + red[r];
    __syncthreads();
  }
  // U[c][il] = M^i (xv + h_i k1), i = w*64 + il   (overwrites uv/accv region)
  for (int idx = t; idx < 64*128; idx += 256) {
    int il = idx >> 7, c = idx & 127;
    int i = w*64 + il;
    float val = 0.f;
    if (i >= 1) {
      float hi = i * DTF;
      #pragma unroll
      for (int m = 0; m <= 4; ++m) val = fmaf(cfs[il][m], za[m][c] + hi*zb[m][c], val);
    }
    uni[c*68 + il] = val;
  }
  __syncthreads();
  // k2[r][il] = sum_c A_J[r][c] U[c][il]
  int rg = t >> 4, i0 = (t & 15) << 2;
  F4 acc[8];
  #pragma unroll
  for (int k = 0; k < 8; ++k)
    #pragma unroll
    for (int e = 0; e < 4; ++e) acc[k].v[e] = 0.f;
  for (int c = 0; c < 128; ++c) {
    F4 bvv = *(const F4*)&uni[c*68 + i0];
    #pragma unroll
    for (int k = 0; k < 8; ++k) {
      float a = XT[c][rg + 16*k];
      #pragma unroll
      for (int e = 0; e < 4; ++e) acc[k].v[e] = fmaf(a, bvv.v[e], acc[k].v[e]);
    }
  }
  #pragma unroll
  for (int k = 0; k < 8; ++k) {
    int rr = rg + 16*k;
    float xr = xv[rr], kr = kv[rr];
    #pragma unroll
    for (int e = 0; e < 4; ++e) {
      int il = i0 + e;
      int i = w*64 + il;
      if (i >= 1) {
        float hi = i * DTF;
        out[(size_t)(256*J + i)*ROW + rr] = xr + 0.5f*hi*(kr + acc[k].v[e]);
      }
    }
  }
}

// ---------------- host ----------------
static void pmul16(const double* a, const double* b, double* o) {
  double r[16];
  for (int i = 0; i < 16; ++i) r[i] = 0.0;
  for (int i = 0; i < 16; ++i) {
    double ai = a[i];
    if (ai == 0.0) continue;
    for (int k = 0; i + k < 16; ++k) r[i+k] += ai*b[k];
  }
  for (int i = 0; i < 16; ++i) o[i] = r[i];
}

extern "C" void kernel_launch(void* const* d_in, const int* in_sizes, int n_in,
                              void* d_out, int out_size, void* d_ws, size_t ws_size,
                              hipStream_t stream) {
  (void)in_sizes; (void)n_in; (void)out_size; (void)ws_size;
  const float* y0 = (const float*)d_in[1];
  const float* Bm = (const float*)d_in[2];
  float* out = (float*)d_out;
  float* ws  = (float*)d_ws;

  // Tsit5 stability polynomial M(z), z = dt*B, via C_s recurrence
  double At[7][7]; memset(At, 0, sizeof(At));
  At[2][1] = 0.161;
  At[3][1] = -0.008480655492356989; At[3][2] = 0.335480655492357;
  At[4][1] = 2.8971530571054935;  At[4][2] = -6.359448489975075;  At[4][3] = 4.3622954328695815;
  At[5][1] = 5.325864828439257;   At[5][2] = -11.748883564062828; At[5][3] = 7.4955393428898365;  At[5][4] = -0.09249506636175525;
  At[6][1] = 5.86145544294642;    At[6][2] = -12.92096931784711;  At[6][3] = 8.159367898576159;   At[6][4] = -0.071584973281401; At[6][5] = -0.028269050394068383;
  const double dB[7] = {0, 0.09646076681806523, 0.01, 0.4798896504144996,
                        1.379008574103742, -3.290069515436081, 2.324710524099774};
  double C[7][16]; memset(C, 0, sizeof(C));
  C[1][0] = 1.0;
  for (int s = 2; s <= 6; ++s) {
    C[s][0] = 1.0;
    for (int k = 1; k < 16; ++k) {
      double acc = 0.0;
      for (int l = 1; l < s; ++l) acc += At[s][l]*C[l][k-1];
      C[s][k] = acc;
    }
  }
  double M[16]; memset(M, 0, sizeof(M)); M[0] = 1.0;
  for (int k = 1; k < 16; ++k) {
    double acc = 0.0;
    for (int s = 1; s <= 6; ++s) acc += dB[s]*C[s][k-1];
    M[k] = acc;
  }
  double p64m[16]; p64m[0] = 1.0;
  for (int m = 1; m < 16; ++m) p64m[m] = p64m[m-1]*64.0;

  // harvest scaled coefficient rows of M^n along one pmul chain
  CFX cfx; memset(&cfx, 0, sizeof(cfx));
  CMB cmb; memset(&cmb, 0, sizeof(cmb));
  double cur[16]; memset(cur, 0, sizeof(cur)); cur[0] = 1.0;
  for (int n = 0; n <= 4032; ++n) {
    if (n < 64)  for (int m = 0; m <= 4; ++m) cfx.cf[n][m] = (float)(cur[m]/p64m[m]);
    if ((n & 63) == 0) {
      int j = n >> 6;
      if (j < 64) for (int m = 0; m <= 6; ++m) cfx.cx[j][m] = (float)(cur[m]/p64m[m]);
    }
    if ((n & 255) == 0) {
      int J = n >> 8;
      if (J <= 15) for (int m = 0; m <= 6; ++m) cmb.c[J][m] = (float)(cur[m]/p64m[m]);
    }
    if ((n & 255) == 128) {
      int J = (n - 128) >> 8;
      if (J <= 14) for (int m = 0; m <= 6; ++m) cmb.c[16+J][m] = (float)(cur[m]/p64m[m]);
    }
    pmul16(cur, M, cur);
  }

  // EK: [z^m](M-1)^k / 64^m for the closed-form M^i coefficients
  EK ek; memset(&ek, 0, sizeof(ek));
  {
    double e1[5] = {0,0,0,0,0}, e2[5] = {0,0,0,0,0}, e3[5] = {0,0,0,0,0}, e4[5] = {0,0,0,0,0};
    for (int m = 1; m <= 4; ++m) e1[m] = M[m];
    for (int m = 2; m <= 4; ++m) for (int a = 1; a < m; ++a) e2[m] += e1[a]*e1[m-a];
    for (int m = 3; m <= 4; ++m) for (int a = 2; a < m; ++a) e3[m] += e2[a]*e1[m-a];
    e4[4] = e3[3]*e1[1];
    for (int m = 1; m <= 4; ++m) {
      ek.e[0][m-1] = e1[m]/p64m[m];
      ek.e[1][m-1] = e2[m]/p64m[m];
      ek.e[2][m-1] = e3[m]/p64m[m];
      ek.e[3][m-1] = e4[m]/p64m[m];
    }
  }

  k_vchain<<<309, 256, 0, stream>>>(y0, Bm, ws, out, cmb);
  k_fused<<<1088, 256, 0, stream>>>(ws, out, ek, cfx);
}